// Round 5
// baseline (726.179 us; speedup 1.0000x reference)
//
#include <hip/hip_runtime.h>

// ChairMLP forward, fused single kernel. N=65536 points, H=60.
// Outputs (flat, fp32): out[N,1] | S[N,4,60] | alk1..alk4[N,4,60] | zs[N,4,1]
//
// 4 threads per point. Lane r (= tid&3):
//   - row-chain r of the affine chain (r<3: P rows, r==3: bias row)
//   - h-chain outputs j = 4*jj + r
// h exchanged via LDS (stride 68 -> max 2-way bank alias, free).
// Row chain lives ENTIRELY in registers: nrow[60] is kept (not re-read from
// global as in round 4 -- that global round-trip was the 80% stall).
// Co-live peak ~ row[60]+nrow[48]+acc[12] => cap VGPR via launch_bounds(256,3).
// One barrier per layer: the only cross-wave hazard is
//   h-phase(k) reads hb[b] -> h-phase(k+1) writes hb[b], separated by the
//   post-h-phase barrier. Row-phase only reads buffers written before that
//   same barrier.

constexpr int  NP = 65536;
constexpr int  HD = 60;
constexpr long CH = (long)NP * 4 * HD;
constexpr long OFF_OUT  = 0;
constexpr long OFF_S    = NP;
constexpr long OFF_ALK1 = OFF_S + CH;
constexpr long OFF_ZS   = OFF_ALK1 + 4 * CH;

__global__ __launch_bounds__(256, 3) void chair_fused(
    const float* __restrict__ x,
    const float* __restrict__ w1, const float* __restrict__ b1,
    const float* __restrict__ w2, const float* __restrict__ b2,
    const float* __restrict__ w3, const float* __restrict__ b3,
    const float* __restrict__ w4, const float* __restrict__ b4,
    const float* __restrict__ w5, const float* __restrict__ b5,
    float* __restrict__ out)
{
    __shared__ float hb[2][64][68];   // [buf][local point][60 + pad]

    const int tid = threadIdx.x;
    const int lp  = tid >> 2;          // local point 0..63
    const int r   = tid & 3;           // row / quarter index
    const int n   = blockIdx.x * 64 + lp;
    const long t  = (long)n * 4 + r;
    const bool isb = (r == 3);
    float* Sp = out + OFF_S + (long)n * (4 * HD);

    // ---------------- layer 1 ----------------
    const float x0 = x[3*n+0], x1 = x[3*n+1], x2 = x[3*n+2];
#pragma unroll
    for (int jj = 0; jj < 15; ++jj) {
        const int j = 4*jj + r;
        float acc = b1[j];
        acc = fmaf(x0, w1[3*j+0], acc);
        acc = fmaf(x1, w1[3*j+1], acc);
        acc = fmaf(x2, w1[3*j+2], acc);
        Sp[j] = acc > 0.f ? 1.f : 0.f;
        hb[1][lp][j] = acc > 0.f ? acc : 0.f;
    }
    __syncthreads();

    // row init: alk1 = (r<3 ? w1.T[r] : b1); row1 = alk1 * s1
    float row[60];
    {
        float* alkp = out + OFF_ALK1 + t * HD;
#pragma unroll
        for (int c0 = 0; c0 < 60; c0 += 4) {
            float4 wv;
            wv.x = isb ? b1[c0+0] : w1[3*(c0+0) + r];
            wv.y = isb ? b1[c0+1] : w1[3*(c0+1) + r];
            wv.z = isb ? b1[c0+2] : w1[3*(c0+2) + r];
            wv.w = isb ? b1[c0+3] : w1[3*(c0+3) + r];
            *reinterpret_cast<float4*>(alkp + c0) = wv;
            float4 hp = *reinterpret_cast<const float4*>(&hb[1][lp][c0]);
            row[c0+0] = hp.x > 0.f ? wv.x : 0.f;
            row[c0+1] = hp.y > 0.f ? wv.y : 0.f;
            row[c0+2] = hp.z > 0.f ? wv.z : 0.f;
            row[c0+3] = hp.w > 0.f ? wv.w : 0.f;
        }
    }

    float zacc = isb ? b5[0] : 0.f;

    // ---------------- layers 2..4 ----------------
#pragma unroll 1
    for (int k = 2; k <= 4; ++k) {
        const float* __restrict__ W = (k == 2) ? w2 : ((k == 3) ? w3 : w4);
        const float* __restrict__ B = (k == 2) ? b2 : ((k == 3) ? b3 : b4);
        const int bc = k & 1;              // current h buffer
        const int bp = (k - 1) & 1;        // previous h buffer

        // ---- h-phase: my quarter of h_k (4 independent FMA chains) ----
        {
            float h[60];
#pragma unroll
            for (int c0 = 0; c0 < 60; c0 += 4)
                *reinterpret_cast<float4*>(&h[c0]) =
                    *reinterpret_cast<const float4*>(&hb[bp][lp][c0]);
            float* Sk = Sp + (k-1) * HD;
#pragma unroll 1
            for (int jj = 0; jj < 15; ++jj) {
                const int j = 4*jj + r;
                const float* wr = W + j * HD;
                float a0 = B[j], a1 = 0.f, a2 = 0.f, a3 = 0.f;
#pragma unroll
                for (int q = 0; q < 15; q += 4) {   // q, q+1, q+2, q+3 -> chains 0..3
                    {
                        float4 wv = *reinterpret_cast<const float4*>(wr + 4*q);
                        a0 = fmaf(h[4*q+0], wv.x, a0); a0 = fmaf(h[4*q+1], wv.y, a0);
                        a0 = fmaf(h[4*q+2], wv.z, a0); a0 = fmaf(h[4*q+3], wv.w, a0);
                    }
                    if (q + 1 < 15) {
                        float4 wv = *reinterpret_cast<const float4*>(wr + 4*(q+1));
                        a1 = fmaf(h[4*q+4], wv.x, a1); a1 = fmaf(h[4*q+5], wv.y, a1);
                        a1 = fmaf(h[4*q+6], wv.z, a1); a1 = fmaf(h[4*q+7], wv.w, a1);
                    }
                    if (q + 2 < 15) {
                        float4 wv = *reinterpret_cast<const float4*>(wr + 4*(q+2));
                        a2 = fmaf(h[4*q+8],  wv.x, a2); a2 = fmaf(h[4*q+9],  wv.y, a2);
                        a2 = fmaf(h[4*q+10], wv.z, a2); a2 = fmaf(h[4*q+11], wv.w, a2);
                    }
                    if (q + 3 < 15) {
                        float4 wv = *reinterpret_cast<const float4*>(wr + 4*(q+3));
                        a3 = fmaf(h[4*q+12], wv.x, a3); a3 = fmaf(h[4*q+13], wv.y, a3);
                        a3 = fmaf(h[4*q+14], wv.z, a3); a3 = fmaf(h[4*q+15], wv.w, a3);
                    }
                }
                float acc = (a0 + a1) + (a2 + a3);
                Sk[j] = acc > 0.f ? 1.f : 0.f;
                hb[bc][lp][j] = acc > 0.f ? acc : 0.f;
            }
        }
        __syncthreads();

        // ---- row-phase: nrow = row @ W.T (+B if bias row); keep in regs ----
        {
            float nrow[60];
            float* alkc = out + OFF_ALK1 + (long)(k-1) * CH + t * HD;
#pragma unroll 1
            for (int j0 = 0; j0 < 60; j0 += 12) {
                float acc[12];
#pragma unroll
                for (int jj = 0; jj < 12; ++jj) acc[jj] = isb ? B[j0+jj] : 0.f;
#pragma unroll
                for (int jj = 0; jj < 12; ++jj) {
                    const float* wr = W + (j0+jj) * HD;
#pragma unroll
                    for (int c = 0; c < 60; ++c)
                        acc[jj] = fmaf(row[c], wr[c], acc[jj]);
                }
#pragma unroll
                for (int jj = 0; jj < 12; jj += 4) {
                    float4 v = { acc[jj], acc[jj+1], acc[jj+2], acc[jj+3] };
                    *reinterpret_cast<float4*>(alkc + j0 + jj) = v;
                }
#pragma unroll
                for (int jj = 0; jj < 12; ++jj) nrow[j0+jj] = acc[jj];
            }
            // next row = nrow * s_k (mask from hb[bc], written pre-barrier)
#pragma unroll
            for (int c0 = 0; c0 < 60; c0 += 4) {
                float4 hp = *reinterpret_cast<const float4*>(&hb[bc][lp][c0]);
                row[c0+0] = hp.x > 0.f ? nrow[c0+0] : 0.f;
                row[c0+1] = hp.y > 0.f ? nrow[c0+1] : 0.f;
                row[c0+2] = hp.z > 0.f ? nrow[c0+2] : 0.f;
                row[c0+3] = hp.w > 0.f ? nrow[c0+3] : 0.f;
            }
        }
        if (k == 4) {
#pragma unroll
            for (int c = 0; c < 60; ++c)
                zacc = fmaf(row[c], w5[c], zacc);   // row == P4/B4 row now
        }
    }

    out[OFF_ZS + t] = zacc;

    // out[n] = h4 . w5 + b5  (h4 lives in hb[0])
    if (r == 0) {
        float acc = b5[0];
#pragma unroll
        for (int c0 = 0; c0 < 60; c0 += 4) {
            float4 hv = *reinterpret_cast<const float4*>(&hb[0][lp][c0]);
            float4 wv = *reinterpret_cast<const float4*>(w5 + c0);
            acc = fmaf(hv.x, wv.x, acc);
            acc = fmaf(hv.y, wv.y, acc);
            acc = fmaf(hv.z, wv.z, acc);
            acc = fmaf(hv.w, wv.w, acc);
        }
        out[OFF_OUT + n] = acc;
    }
}

extern "C" void kernel_launch(void* const* d_in, const int* in_sizes, int n_in,
                              void* d_out, int out_size, void* d_ws, size_t ws_size,
                              hipStream_t stream) {
    const float* x  = (const float*)d_in[0];
    const float* w1 = (const float*)d_in[1];
    const float* b1 = (const float*)d_in[2];
    const float* w2 = (const float*)d_in[3];
    const float* b2 = (const float*)d_in[4];
    const float* w3 = (const float*)d_in[5];
    const float* b3 = (const float*)d_in[6];
    const float* w4 = (const float*)d_in[7];
    const float* b4 = (const float*)d_in[8];
    const float* w5 = (const float*)d_in[9];
    const float* b5 = (const float*)d_in[10];
    float* out = (float*)d_out;

    chair_fused<<<NP / 64, 256, 0, stream>>>(
        x, w1, b1, w2, b2, w3, b3, w4, b4, w5, b5, out);
}